// Round 3
// baseline (253.637 us; speedup 1.0000x reference)
//
#include <hip/hip_runtime.h>
#include <stdint.h>

// GAT 3-layer + linear head, MI355X (gfx950).
// I/O is FP32 (per reference). Internals: bf16 MFMA for h and att@h
// (softmax-averaging damps bf16 rounding); logits and final linear in fp32.
// R9: arithmetic-intensity + occupancy.
//   - k_attn M-block x2: 2 j-groups x 2 waves x 32 i-rows/wave. Each LDS
//     B-fragment feeds TWO MFMAs (A-frags for rows 0-15/16-31) -> LDS B-read
//     traffic halves (was the post-R8 bottleneck: 2MB/CU per launch vs 4.7us
//     MFMA floor). 3-slot ring + counted vmcnt kept. e-prefetch regs dropped
//     (e is LDS-resident; saves 32 VGPR).
//   - k_h output-half split: grid (8,64), 2 blocks/CU (was 1 block = 1
//     wave/SIMD, x-load latency fully exposed).

typedef unsigned short u16;
typedef __bf16 bf16x8 __attribute__((ext_vector_type(8)));
typedef float f32x4 __attribute__((ext_vector_type(4)));
typedef u16 u16x8 __attribute__((ext_vector_type(8)));

#define LOG2E 1.44269504088896340736f

__device__ __forceinline__ float b2f(u16 u) {
    union { unsigned int i; float f; } v; v.i = ((unsigned int)u) << 16; return v.f;
}
__device__ __forceinline__ u16 f2b(float f) {   // RNE round to bf16
    union { float f; unsigned int i; } v; v.f = f;
    unsigned int i = v.i;
    return (u16)((i + 0x7fffu + ((i >> 16) & 1u)) >> 16);
}
__device__ __forceinline__ float fast_exp2(float x) {
#if __has_builtin(__builtin_amdgcn_exp2f)
    return __builtin_amdgcn_exp2f(x);
#else
    return exp2f(x);
#endif
}

union ABfrag { bf16x8 v; u16x8 u; };

__device__ __forceinline__ void gload_lds16(const u16* g, u16* l) {
    // async global->LDS, 16B/lane, LDS dest = wave-uniform base + lane*16
    __builtin_amdgcn_global_load_lds((const __attribute__((address_space(1))) void*)g,
                                     (__attribute__((address_space(3))) void*)l,
                                     16, 0, 0);
}

template <int N>
__device__ __forceinline__ void wait_vmcnt() {
    asm volatile("s_waitcnt vmcnt(%0)" :: "i"(N) : "memory");
}
__device__ __forceinline__ void pipe_barrier() {
    __builtin_amdgcn_s_barrier();
    asm volatile("" ::: "memory");   // pin loads below the barrier
}

// ---------------- k_mask: adjacency bitmask, adjm[row][64] uint32 (bit j of row)
__global__ void __launch_bounds__(256) k_mask(const float* __restrict__ adj,
                                              uint32_t* __restrict__ adjm) {
    const int w = threadIdx.x >> 6, lane = threadIdx.x & 63;
    const int row = blockIdx.x * 4 + w;
    const float* ar = adj + (size_t)row * 2048;
    uint32_t* mr = adjm + (size_t)row * 64;
    for (int j0 = 0; j0 < 2048; j0 += 64) {
        unsigned long long m = __ballot(ar[j0 + lane] > 0.f);
        if (lane == 0) {
            mr[(j0 >> 5)] = (uint32_t)m;
            mr[(j0 >> 5) + 1] = (uint32_t)(m >> 32);
        }
    }
}

// ---------------- prep: bf16-transpose W's, u = (W @ a)*log2e (fp32)
__global__ void k_prep(const float* __restrict__ W1, const float* __restrict__ W2,
                       const float* __restrict__ W3,
                       const float* __restrict__ a1s, const float* __restrict__ a1d,
                       const float* __restrict__ a2s, const float* __restrict__ a2d,
                       const float* __restrict__ a3s, const float* __restrict__ a3d,
                       u16* __restrict__ Wt1, u16* __restrict__ Wt2, u16* __restrict__ Wt3,
                       float* __restrict__ u1s, float* __restrict__ u1d,
                       float* __restrict__ u2s, float* __restrict__ u2d,
                       float* __restrict__ u3s, float* __restrict__ u3d) {
    if (blockIdx.x == 160) {                 // u-vectors: fp32 matvecs, trivial size
        int f = threadIdx.x;
        if (f < 128) {
            float s1 = 0.f, d1 = 0.f, s2 = 0.f, d2 = 0.f, s3 = 0.f, d3 = 0.f;
            for (int o = 0; o < 128; ++o) { float w = W1[f * 128 + o]; s1 += w * a1s[o]; d1 += w * a1d[o]; }
            for (int o = 0; o < 128; ++o) { float w = W2[f * 128 + o]; s2 += w * a2s[o]; d2 += w * a2d[o]; }
            for (int o = 0; o <  64; ++o) { float w = W3[f *  64 + o]; s3 += w * a3s[o]; d3 += w * a3d[o]; }
            u1s[f] = s1 * LOG2E; u1d[f] = d1 * LOG2E;
            u2s[f] = s2 * LOG2E; u2d[f] = d2 * LOG2E;
            u3s[f] = s3 * LOG2E; u3d[f] = d3 * LOG2E;
        }
        return;
    }
    int idx = blockIdx.x * 256 + threadIdx.x;
    if (idx < 16384) {                       // W1: [128,128] -> Wt1[o][f] bf16
        int f = idx >> 7, o = idx & 127;
        Wt1[o * 128 + f] = f2b(W1[idx]);
    } else if (idx < 32768) {                // W2
        int j = idx - 16384; int f = j >> 7, o = j & 127;
        Wt2[o * 128 + f] = f2b(W2[j]);
    } else if (idx < 40960) {                // W3: [128,64] -> Wt3[o][f]
        int j = idx - 32768; int f = j >> 6, o = j & 63;
        Wt3[o * 128 + f] = f2b(W3[j]);
    }
}

// ---------------- k_h: h = act @ W (bf16 MFMA) -> h^T bf16;
// logits -> exponentials: esf[i] = (2^es, 2^0.2es), edf[i] = (2^ed, 2^0.2ed)
// grid (8, 64) = (b, nblk*2+ohalf): block computes 64 rows x F/2 outputs.
// block 256 (4 waves x 16 rows). K = 128 always. 2 blocks/CU.
template <int F, bool XF32>
__global__ void __launch_bounds__(256) k_h(const void* __restrict__ xv,
                                           const u16* __restrict__ Wt,
                                           const float* __restrict__ us,
                                           const float* __restrict__ ud,
                                           u16* __restrict__ h_t,
                                           float* __restrict__ esf,
                                           float* __restrict__ edf) {
    constexpr int NTB = F / 32;              // output 16-col tiles per block (half of F)
    constexpr int TNP = 72;                  // padded n-stride (144B = 9x16B)
    __shared__ __align__(16) u16 hl[(F / 2) * TNP];

    const int b = blockIdx.x;
    const int nb2 = blockIdx.y;
    const int nblk = nb2 >> 1, ohalf = nb2 & 1;
    const int tid = threadIdx.x;
    const int w = tid >> 6, lane = tid & 63;
    const int quad = lane >> 4, l15 = lane & 15;
    const int n0w = nblk * 64 + w * 16;
    const int i_a = n0w + l15;               // A-operand row (m = lane&15)

    ABfrag afr[4];
    float ps = 0.f, pd = 0.f;
    if (XF32) {
        const float* xr = (const float*)xv + ((size_t)(b * 2048 + i_a)) * 128;
#pragma unroll
        for (int kk = 0; kk < 4; ++kk) {
            const int o8 = kk * 32 + quad * 8;
            float4 x0 = *reinterpret_cast<const float4*>(xr + o8);
            float4 x1 = *reinterpret_cast<const float4*>(xr + o8 + 4);
            float4 s0 = *reinterpret_cast<const float4*>(us + o8);
            float4 s1 = *reinterpret_cast<const float4*>(us + o8 + 4);
            float4 d0 = *reinterpret_cast<const float4*>(ud + o8);
            float4 d1 = *reinterpret_cast<const float4*>(ud + o8 + 4);
            ps += x0.x * s0.x + x0.y * s0.y + x0.z * s0.z + x0.w * s0.w
                + x1.x * s1.x + x1.y * s1.y + x1.z * s1.z + x1.w * s1.w;
            pd += x0.x * d0.x + x0.y * d0.y + x0.z * d0.z + x0.w * d0.w
                + x1.x * d1.x + x1.y * d1.y + x1.z * d1.z + x1.w * d1.w;
            afr[kk].u[0] = f2b(x0.x); afr[kk].u[1] = f2b(x0.y);
            afr[kk].u[2] = f2b(x0.z); afr[kk].u[3] = f2b(x0.w);
            afr[kk].u[4] = f2b(x1.x); afr[kk].u[5] = f2b(x1.y);
            afr[kk].u[6] = f2b(x1.z); afr[kk].u[7] = f2b(x1.w);
        }
    } else {
        const u16* xr = (const u16*)xv + ((size_t)(b * 2048 + i_a)) * 128;
#pragma unroll
        for (int kk = 0; kk < 4; ++kk) {
            const int o8 = kk * 32 + quad * 8;
            u16x8 xa = *reinterpret_cast<const u16x8*>(xr + o8);
            afr[kk].u = xa;
            float4 s0 = *reinterpret_cast<const float4*>(us + o8);
            float4 s1 = *reinterpret_cast<const float4*>(us + o8 + 4);
            float4 d0 = *reinterpret_cast<const float4*>(ud + o8);
            float4 d1 = *reinterpret_cast<const float4*>(ud + o8 + 4);
            float xf[8];
#pragma unroll
            for (int j = 0; j < 8; ++j) xf[j] = b2f(xa[j]);
            ps += xf[0] * s0.x + xf[1] * s0.y + xf[2] * s0.z + xf[3] * s0.w
                + xf[4] * s1.x + xf[5] * s1.y + xf[6] * s1.z + xf[7] * s1.w;
            pd += xf[0] * d0.x + xf[1] * d0.y + xf[2] * d0.z + xf[3] * d0.w
                + xf[4] * d1.x + xf[5] * d1.y + xf[6] * d1.z + xf[7] * d1.w;
        }
    }
    if (ohalf == 0) {
        // reduce logit partials across the 4 quads sharing l15 (full 128-dot)
        ps += __shfl_xor(ps, 16, 64); ps += __shfl_xor(ps, 32, 64);
        pd += __shfl_xor(pd, 16, 64); pd += __shfl_xor(pd, 32, 64);
        if (quad == 0) {
            const size_t idx = (size_t)(b * 2048 + i_a) * 2;
            float2 sv; sv.x = fast_exp2(ps); sv.y = fast_exp2(0.2f * ps);
            float2 dv; dv.x = fast_exp2(pd); dv.y = fast_exp2(0.2f * pd);
            *reinterpret_cast<float2*>(esf + idx) = sv;   // (Es, Fs)
            *reinterpret_cast<float2*>(edf + idx) = dv;   // (Ed, Fd)
        }
    }

    f32x4 acc[NTB];
#pragma unroll
    for (int nt = 0; nt < NTB; ++nt) acc[nt] = (f32x4){0.f, 0.f, 0.f, 0.f};
#pragma unroll
    for (int kk = 0; kk < 4; ++kk) {
#pragma unroll
        for (int nt = 0; nt < NTB; ++nt) {
            bf16x8 bfv = *reinterpret_cast<const bf16x8*>(
                Wt + (ohalf * (F / 2) + nt * 16 + l15) * 128 + kk * 32 + quad * 8);
            acc[nt] = __builtin_amdgcn_mfma_f32_16x16x32_bf16(afr[kk].v, bfv, acc[nt], 0, 0, 0);
        }
    }

    // stage transposed tile to LDS (D: col=l15 -> o, row=quad*4+r -> i), then
    // coalesced global write of h^T[b][o][n]
#pragma unroll
    for (int nt = 0; nt < NTB; ++nt)
#pragma unroll
        for (int r = 0; r < 4; ++r)
            hl[(nt * 16 + l15) * TNP + w * 16 + quad * 4 + r] = f2b(acc[nt][r]);
    __syncthreads();
    if (tid < F) {                            // F/2 outputs x 2 col-halves
        int o_loc = tid >> 1, half32 = tid & 1;
        const u16* src = hl + o_loc * TNP + half32 * 32;
        u16* dst = h_t + ((size_t)(b * F + ohalf * (F / 2) + o_loc)) * 2048
                   + nblk * 64 + half32 * 32;
#pragma unroll
        for (int c = 0; c < 4; ++c)
            *reinterpret_cast<u16x8*>(dst + c * 8) =
                *reinterpret_cast<const u16x8*>(src + c * 8);
    }
}

// ---------------- k_attn: fused masked-softmax(P) @ H, counted-vmcnt pipeline.
// grid (8, 32) = (b, iblk), block 256 = 2 j-groups x 2 waves x 32 i-rows/wave.
// M-block x2: each wave owns TWO 16-row A-fragments; every LDS B-fragment
// read feeds 2 MFMAs (halves LDS B-read traffic vs 4-wave groups).
// 3-slot LDS ring per group; tile j+2 issued at iter j, waited (vmcnt(G)) at
// iter j+2; raw s_barrier (no vmcnt(0) drain in loop). e + masks LDS-resident.
template <int F, bool OUT_F32>
__global__ void __launch_bounds__(256) k_attn(const float* __restrict__ esf,
                                              const float* __restrict__ edf,
                                              const uint32_t* __restrict__ adjm,
                                              const u16* __restrict__ h_t,
                                              void* __restrict__ outp) {
    constexpr int NT = F / 16;                       // output col tiles per wave
    constexpr int G  = F / 16;                       // gload_lds ops per wave per tile
    __shared__ __align__(16) u16 Ht[2][3][F * 64];   // [grp][slot], xor-swizzled tiles
    __shared__ __align__(16) float eL[4096];         // (Ed,Fd) all 2048 j (16 KB)
    __shared__ __align__(16) uint32_t mL[64 * 64];   // mask pairs, xor-swizzled (16 KB)
    float* accLDS = (float*)&Ht[0][0][0];            // combine area (aliases tiles)

    const int b = blockIdx.x;
    const int iblk = blockIdx.y;
    const int tid = threadIdx.x;
    const int grp = tid >> 7;                 // j-group 0/1 (128 threads each)
    const int t128 = tid & 127;
    const int w = t128 >> 6;                  // wave-within-group: rows w*32..+31
    const int lane = tid & 63;
    const int quad = lane >> 4, l15 = lane & 15;
    const int r0 = w * 32 + l15;              // frag0 block-local row
    const int r1 = r0 + 16;                   // frag1 block-local row

    const float2 e0 = *reinterpret_cast<const float2*>(esf + ((size_t)(b * 2048 + iblk * 64 + r0)) * 2);
    const float2 e1 = *reinterpret_cast<const float2*>(esf + ((size_t)(b * 2048 + iblk * 64 + r1)) * 2);
    const float Es0 = e0.x, Fs0 = e0.y, Es1 = e1.x, Fs1 = e1.y;
    const u16* hb = h_t + (size_t)b * F * 2048;

    const int lro = lane >> 3;
    const int lcp = lane & 7;
    const int jt0 = grp * 16;                 // this group's jt range [jt0, jt0+16)

    ABfrag onesf;                             // all-ones B operand (denominator)
#pragma unroll
    for (int j = 0; j < 8; ++j) onesf.u[j] = 0x3F80;   // bf16(1.0)

    f32x4 acc0[NT], acc1[NT];
#pragma unroll
    for (int nt = 0; nt < NT; ++nt) {
        acc0[nt] = (f32x4){0.f, 0.f, 0.f, 0.f};
        acc1[nt] = (f32x4){0.f, 0.f, 0.f, 0.f};
    }
    f32x4 d0 = (f32x4){0.f, 0.f, 0.f, 0.f};
    f32x4 d1 = (f32x4){0.f, 0.f, 0.f, 0.f};

    // ---- prologue: e-vectors + masks -> LDS (once)
    {
        const float4* esrc = (const float4*)(edf + (size_t)b * 4096);
        float4* edst = (float4*)eL;
#pragma unroll
        for (int t = 0; t < 4; ++t) edst[tid + t * 256] = esrc[tid + t * 256];
        const uint2* msrc = (const uint2*)(adjm + (size_t)(iblk * 64) * 64);
#pragma unroll
        for (int t = 0; t < 8; ++t) {
            int idx = tid + t * 256;
            int r = idx >> 5, k = idx & 31;   // row r (0..63), pair k (0..31)
            uint2 v = msrc[idx];
            *reinterpret_cast<uint2*>((char*)mL + r * 256 + ((k ^ (r & 31)) * 8)) = v;
        }
    }

    auto STAGE = [&](int jt, int slot) {
        const int j0 = jt * 64;
        u16* lbase = &Ht[grp][slot][0];
#pragma unroll
        for (int it = 0; it < G; ++it) {
            int ci = it * 2 + w;              // 8-row chunk index
            int ro = ci * 8 + lro;
            int c = lcp ^ (ro & 7);
            gload_lds16(hb + (size_t)ro * 2048 + j0 + c * 8, lbase + ci * 512);
        }
    };

    f32x4 ec[8]; uint2 mc0, mc1;
    auto loadE = [&](int jt) {
        const float* eb = eL + (size_t)(jt * 64 + quad * 8) * 2;
#pragma unroll
        for (int q = 0; q < 4; ++q) ec[q] = *reinterpret_cast<const f32x4*>(eb + q * 4);
#pragma unroll
        for (int q = 0; q < 4; ++q) ec[4 + q] = *reinterpret_cast<const f32x4*>(eb + 64 + q * 4);
        mc0 = *reinterpret_cast<const uint2*>((const char*)mL + r0 * 256 + ((jt ^ (r0 & 31)) * 8));
        mc1 = *reinterpret_cast<const uint2*>((const char*)mL + r1 * 256 + ((jt ^ (r1 & 31)) * 8));
    };

    auto compute = [&](int slot) {
        // P fragments (both row-sets) in A-operand layout: max(Es*Ed, Fs*Fd), masked.
        ABfrag af0[2], af1[2];
#pragma unroll
        for (int kk = 0; kk < 2; ++kk) {
            const uint32_t word0 = kk ? mc0.y : mc0.x;
            const uint32_t word1 = kk ? mc1.y : mc1.x;
#pragma unroll
            for (int px = 0; px < 4; ++px) {
                const f32x4 q = ec[kk * 4 + px];          // (Ed0,Fd0,Ed1,Fd1)
                const int bsh = quad * 8 + px * 2;
                float wa0 = fmaxf(Es0 * q.x, Fs0 * q.y);
                float wb0 = fmaxf(Es0 * q.z, Fs0 * q.w);
                float wa1 = fmaxf(Es1 * q.x, Fs1 * q.y);
                float wb1 = fmaxf(Es1 * q.z, Fs1 * q.w);
                const uint32_t sa0 = 0u - ((word0 >> bsh) & 1u);
                const uint32_t sb0 = 0u - ((word0 >> (bsh + 1)) & 1u);
                const uint32_t sa1 = 0u - ((word1 >> bsh) & 1u);
                const uint32_t sb1 = 0u - ((word1 >> (bsh + 1)) & 1u);
                wa0 = __uint_as_float(__float_as_uint(wa0) & sa0);
                wb0 = __uint_as_float(__float_as_uint(wb0) & sb0);
                wa1 = __uint_as_float(__float_as_uint(wa1) & sa1);
                wb1 = __uint_as_float(__float_as_uint(wb1) & sb1);
                af0[kk].v[px * 2]     = (__bf16)wa0;      // hw v_cvt_pk_bf16_f32
                af0[kk].v[px * 2 + 1] = (__bf16)wb0;
                af1[kk].v[px * 2]     = (__bf16)wa1;
                af1[kk].v[px * 2 + 1] = (__bf16)wb1;
            }
        }
        const u16* tb = &Ht[grp][slot][0];
        __builtin_amdgcn_s_setprio(1);
#pragma unroll
        for (int kk = 0; kk < 2; ++kk) {
#pragma unroll
            for (int nt = 0; nt < NT; ++nt) {
                int ob = nt * 16 + l15;
                int c = kk * 4 + quad;
                bf16x8 bfv = *reinterpret_cast<const bf16x8*>(
                    tb + ob * 64 + ((c ^ (ob & 7)) * 8));
                acc0[nt] = __builtin_amdgcn_mfma_f32_16x16x32_bf16(af0[kk].v, bfv, acc0[nt], 0, 0, 0);
                acc1[nt] = __builtin_amdgcn_mfma_f32_16x16x32_bf16(af1[kk].v, bfv, acc1[nt], 0, 0, 0);
            }
            d0 = __builtin_amdgcn_mfma_f32_16x16x32_bf16(af0[kk].v, onesf.v, d0, 0, 0, 0);
            d1 = __builtin_amdgcn_mfma_f32_16x16x32_bf16(af1[kk].v, onesf.v, d1, 0, 0, 0);
        }
        __builtin_amdgcn_s_setprio(0);
    };

    __syncthreads();                          // eL/mL visible (one-time full drain)
    STAGE(jt0, 0);                            // tiles 0,1 in flight
    STAGE(jt0 + 1, 1);

    int sc = 0, sp = 2;
    for (int jj = 0; jj < 15; ++jj) {
        wait_vmcnt<G>();                      // tile jj landed; tile jj+1 stays in flight
        pipe_barrier();                       // all waves' tile-jj DMA visible
        if (jj < 14) STAGE(jt0 + jj + 2, sp); // 2-iter-deep prefetch
        loadE(jt0 + jj);                      // LDS reads (lgkm domain)
        compute(sc);
        sc = (sc == 2) ? 0 : sc + 1;
        sp = (sp == 2) ? 0 : sp + 1;
    }
    wait_vmcnt<0>();                          // last tile
    pipe_barrier();
    loadE(jt0 + 15);
    compute(sc);

    __syncthreads();                          // tile reads done; accLDS alias safe
    // cross-group combine: grp1 exports acc + denom partials through dead tile LDS
    if (grp == 1) {
        f32x4* basep = reinterpret_cast<f32x4*>(&accLDS[(size_t)t128 * (2 * NT + 2) * 4]);
#pragma unroll
        for (int nt = 0; nt < NT; ++nt) { basep[nt] = acc0[nt]; basep[NT + nt] = acc1[nt]; }
        basep[2 * NT] = d0;
        basep[2 * NT + 1] = d1;
    }
    __syncthreads();
    if (grp == 0) {
        const f32x4* basep = reinterpret_cast<const f32x4*>(&accLDS[(size_t)t128 * (2 * NT + 2) * 4]);
#pragma unroll
        for (int nt = 0; nt < NT; ++nt) { acc0[nt] += basep[nt]; acc1[nt] += basep[NT + nt]; }
        d0 += basep[2 * NT];
        d1 += basep[2 * NT + 1];
        float dinv0[4], dinv1[4];
#pragma unroll
        for (int r = 0; r < 4; ++r) {
            dinv0[r] = 1.0f / fmaxf(d0[r], 1e-30f);   // rowsum(P), rows r0-set
            dinv1[r] = 1.0f / fmaxf(d1[r], 1e-30f);   // rows r1-set
        }
        const int ib0 = iblk * 64 + w * 32 + quad * 4;        // frag0 rows + r
        const int ib1 = ib0 + 16;                             // frag1 rows + r
        if (OUT_F32) {
            float* o3 = (float*)outp;
#pragma unroll
            for (int nt = 0; nt < NT; ++nt)
#pragma unroll
                for (int r = 0; r < 4; ++r) {
                    float v0 = fmaxf(acc0[nt][r] * dinv0[r], 0.f);   // relu
                    float v1 = fmaxf(acc1[nt][r] * dinv1[r], 0.f);
                    o3[((size_t)(b * 2048 + ib0 + r)) * F + nt * 16 + l15] = v0;
                    o3[((size_t)(b * 2048 + ib1 + r)) * F + nt * 16 + l15] = v1;
                }
        } else {
            u16* xo = (u16*)outp;
#pragma unroll
            for (int nt = 0; nt < NT; ++nt)
#pragma unroll
                for (int r = 0; r < 4; ++r) {
                    float v0 = fmaxf(acc0[nt][r] * dinv0[r], 0.f);
                    float v1 = fmaxf(acc1[nt][r] * dinv1[r], 0.f);
                    xo[((size_t)(b * 2048 + ib0 + r)) * F + nt * 16 + l15] = f2b(v0);
                    xo[((size_t)(b * 2048 + ib1 + r)) * F + nt * 16 + l15] = f2b(v1);
                }
        }
    }
}

// ---------------- final linear stage 1: [8,131072] fp32 @ [131072,128] fp32
// grid 512, block 256; block p owns k in [p*256,(p+1)*256); writes pbuf[p][b][o].
__global__ void __launch_bounds__(256) k_lin(const float* __restrict__ o3,
                                             const float* __restrict__ Wlin,
                                             float* __restrict__ pbuf) {
    __shared__ float xc[8][256];
    __shared__ float red[8][8][128];          // [kb][b][o] = 32 KB
    const int tid = threadIdx.x;
    const int k0 = blockIdx.x * 256;
    for (int idx = tid; idx < 2048; idx += 256) {
        int bb = idx >> 8, kk = idx & 255;
        xc[bb][kk] = o3[(size_t)bb * 131072 + k0 + kk];
    }
    __syncthreads();
    const int o4 = tid & 31;                  // float4 output group: o = 4*o4..4*o4+3
    const int kb = tid >> 5;                  // k band: 32 k each
    f32x4 acc[8];
#pragma unroll
    for (int bb = 0; bb < 8; ++bb) acc[bb] = (f32x4){0.f, 0.f, 0.f, 0.f};
    const float* wp = Wlin + (size_t)(k0 + kb * 32) * 128 + o4 * 4;
#pragma unroll 4
    for (int k = 0; k < 32; ++k) {
        f32x4 wv = *reinterpret_cast<const f32x4*>(wp + (size_t)k * 128);
#pragma unroll
        for (int bb = 0; bb < 8; ++bb) acc[bb] += wv * xc[bb][kb * 32 + k];
    }
#pragma unroll
    for (int bb = 0; bb < 8; ++bb)
        *reinterpret_cast<f32x4*>(&red[kb][bb][o4 * 4]) = acc[bb];
    __syncthreads();
    // fold 8 k-bands: thread handles 4 flat outputs
    const int f = tid * 4;
    const int bb = f >> 7, o = f & 127;
    f32x4 s = (f32x4){0.f, 0.f, 0.f, 0.f};
#pragma unroll
    for (int k2 = 0; k2 < 8; ++k2) s += *reinterpret_cast<const f32x4*>(&red[k2][bb][o]);
    *reinterpret_cast<f32x4*>(&pbuf[(size_t)blockIdx.x * 1024 + f]) = s;
}

// ---------------- stage 2: fold 512 partials + bias -> out
// grid 64 x 256: block owns 16 outputs; 16 threads/output sum strided partials.
__global__ void __launch_bounds__(256) k_bias(const float* __restrict__ pbuf,
                                              const float* __restrict__ blin,
                                              float* __restrict__ out) {
    __shared__ float red[256];
    const int tid = threadIdx.x;
    const int p16 = tid >> 4;                 // 16 p-groups
    const int fo = tid & 15;
    const int f0 = blockIdx.x * 16;
    float s = 0.f;
#pragma unroll 4
    for (int p = p16; p < 512; p += 16)
        s += pbuf[(size_t)p * 1024 + f0 + fo];
    red[tid] = s;
    __syncthreads();
    if (tid < 16) {
        float t = 0.f;
#pragma unroll
        for (int k = 0; k < 16; ++k) t += red[k * 16 + tid];
        out[f0 + tid] = t + blin[(f0 + tid) & 127];
    }
}

extern "C" void kernel_launch(void* const* d_in, const int* in_sizes, int n_in,
                              void* d_out, int out_size, void* d_ws, size_t ws_size,
                              hipStream_t stream) {
    (void)in_sizes; (void)n_in; (void)out_size;
    const float* x    = (const float*)d_in[0];
    const float* adj  = (const float*)d_in[1];
    const float* W1   = (const float*)d_in[2];
    const float* a1s  = (const float*)d_in[3];
    const float* a1d  = (const float*)d_in[4];
    const float* W2   = (const float*)d_in[5];
    const float* a2s  = (const float*)d_in[6];
    const float* a2d  = (const float*)d_in[7];
    const float* W3   = (const float*)d_in[8];
    const float* a3s  = (const float*)d_in[9];
    const float* a3d  = (const float*)d_in[10];
    const float* Wlin = (const float*)d_in[11];
    const float* blin = (const float*)d_in[12];

    // ---- workspace layout (adaptive; never early-return) ----
    char* ws = (char*)d_ws;
    u16*   h_t = (u16*)ws;                          // 4 MB  [8][F][2048] bf16
    size_t off = (size_t)4 << 20;
    float* esf = (float*)(ws + off); off += 131072; // [8][2048] x (Es,Fs)
    float* edf = (float*)(ws + off); off += 131072; // [8][2048] x (Ed,Fd)
    u16*   Wt1 = (u16*)(ws + off);   off += 32768;
    u16*   Wt2 = (u16*)(ws + off);   off += 32768;
    u16*   Wt3 = (u16*)(ws + off);   off += 16384;
    float* u1s = (float*)(ws + off); off += 512;
    float* u1d = (float*)(ws + off); off += 512;
    float* u2s = (float*)(ws + off); off += 512;
    float* u2d = (float*)(ws + off); off += 512;
    float* u3s = (float*)(ws + off); off += 512;
    float* u3d = (float*)(ws + off); off += 512;
    uint32_t* adjm = (uint32_t*)(ws + off); off += 524288;    // [2048][64] bitmask
    float* pbuf = (float*)(ws + off); off += (size_t)512 * 1024 * 4;  // 2 MB partials
    // activation ping (bf16 [8][2048][128] = 4MB) aliases layer-3 fp32 out
    // ([8][2048][64] fp32 = 4MB): disjoint live ranges. Fallback: alias the x
    // input (16MB fp32; dead after layer-1 k_h; restored by harness pre-launch).
    u16* actA;
    if (ws_size >= off + ((size_t)4 << 20)) {
        actA = (u16*)(ws + off);
    } else {
        actA = (u16*)d_in[0];
    }
    float* o3 = (float*)actA;

    dim3 g(8, 32);
    dim3 gh(8, 64);
    k_mask<<<512, 256, 0, stream>>>(adj, adjm);
    k_prep<<<161, 256, 0, stream>>>(W1, W2, W3, a1s, a1d, a2s, a2d, a3s, a3d,
                                    Wt1, Wt2, Wt3, u1s, u1d, u2s, u2d, u3s, u3d);

    k_h<128, true ><<<gh, 256, 0, stream>>>((const void*)x, Wt1, u1s, u1d, h_t, esf, edf);
    k_attn<128, false><<<g, 256, 0, stream>>>(esf, edf, adjm, h_t, (void*)actA);

    k_h<128, false><<<gh, 256, 0, stream>>>((const void*)actA, Wt2, u2s, u2d, h_t, esf, edf);
    k_attn<128, false><<<g, 256, 0, stream>>>(esf, edf, adjm, h_t, (void*)actA);

    k_h<64, false><<<gh, 256, 0, stream>>>((const void*)actA, Wt3, u3s, u3d, h_t, esf, edf);
    k_attn<64, true ><<<g, 256, 0, stream>>>(esf, edf, adjm, h_t, (void*)o3);

    k_lin<<<512, 256, 0, stream>>>(o3, Wlin, pbuf);
    k_bias<<<64, 256, 0, stream>>>(pbuf, blin, (float*)d_out);
}